// Round 11
// baseline (151.991 us; speedup 1.0000x reference)
//
#include <hip/hip_runtime.h>
#include <hip/hip_bf16.h>

#define NOBJ 25

typedef short bf16x8 __attribute__((ext_vector_type(8)));
typedef short s16x4 __attribute__((ext_vector_type(4)));
typedef float f32x4 __attribute__((ext_vector_type(4)));
typedef unsigned int uint;

__device__ __forceinline__ short f2bf(float f) {
  __hip_bfloat16 b = __float2bfloat16(f);  // RTN
  return *reinterpret_cast<short*>(&b);
}
__device__ __forceinline__ float bf2f(short s) {
  unsigned u = ((unsigned)(unsigned short)s) << 16;
  return __uint_as_float(u);
}
__device__ __forceinline__ uint packhl(float v) {
  const short hi = f2bf(v);
  const short lo = f2bf(v - bf2f(hi));
  return ((uint)(unsigned short)hi << 16) | (uint)(unsigned short)lo;
}

// Manual grid barrier: per-phase monotonic counter (zeroed by a memset node
// each launch). Device-scope atomics + threadfence per G16. Only thread 0
// spins; s_sleep throttles the coherent-point traffic.
__device__ __forceinline__ void grid_barrier(uint* ctr, int nblk) {
  __syncthreads();
  if (threadIdx.x == 0) {
    __threadfence();                 // release: prior writes visible device-wide
    atomicAdd(ctr, 1u);
    while (__hip_atomic_load(ctr, __ATOMIC_RELAXED, __HIP_MEMORY_SCOPE_AGENT) <
           (uint)nblk) {
      __builtin_amdgcn_s_sleep(2);
    }
    __threadfence();                 // acquire: other blocks' writes visible
  }
  __syncthreads();
}

// ---------------------------------------------------------------------------
// One persistent kernel, 512 blocks x 256 threads (exactly 2 blocks/CU by
// LDS: 63.6KB -> guaranteed co-residency for the spin barrier):
//  phase 0: MLP-weight prep (grid-strided) + conv (R9 verbatim) -> h0p packed
//  phase 1: MLP layer1, 128 m-groups x 4 n-groups, M=8, N=64/block
//  phase 2: MLP layer2 (same geometry)
//  phase 3: layer3 on blocks 0..127, wave 0, M=8
// ---------------------------------------------------------------------------
__global__ __launch_bounds__(256, 2) void mono_kernel(
    const float* __restrict__ x,    // (1024, 25*64)
    const float* __restrict__ cw0, const float* __restrict__ cw1,
    const float* __restrict__ cb,
    const float* __restrict__ w1, const float* __restrict__ w2,
    const float* __restrict__ w3,
    const float* __restrict__ b1, const float* __restrict__ b2,
    const float* __restrict__ b3,
    short* __restrict__ wfm,        // 270336 shorts frag-linear hi/lo
    uint* __restrict__ h0p, uint* __restrict__ h1p, uint* __restrict__ h2p,
    uint* __restrict__ bar,         // 3 counters, 32-uint stride, pre-zeroed
    float* __restrict__ out)        // (1024, 10)
{
  __shared__ short xs[2][32][72];        // 9216 B
  __shared__ float ab[4][2][NOBJ][68];   // 54400 B (per-wave conv scratch)
  // MLP overlay on ab (dead after conv + barrier): [term][8][264] shorts
  short (*Hs)[8][264] = reinterpret_cast<short (*)[8][264]>(&ab[0][0][0][0]);

  const int t = threadIdx.x;
  const int bid = blockIdx.x;
  const int lane = t & 63;
  const int wv = t >> 6;
  const int r = lane & 15;
  const int g = lane >> 4;

  // ==== phase 0a: MLP weight prep (grid-strided over all 131072 threads) ====
  for (int j = bid * 256 + t; j < 270336; j += 512 * 256) {
    const float* w; int term, f, nt;
    const bool isw3 = (j >= 262144);
    if (!isw3) {
      w = (j >> 17) ? w2 : w1;
      const int idx = j & 131071;
      term = idx >> 16; f = idx & 65535; nt = f >> 12;
    } else {
      w = w3;
      const int idx = j - 262144;  // 0..8191
      term = idx >> 12; f = idx & 4095; nt = 0;
    }
    const int ks = (f >> 9) & 7;
    const int l  = (f >> 3) & 63;
    const int jj = f & 7;
    const int col = nt * 16 + (l & 15);
    const int k   = ks * 32 + (l >> 4) * 8 + jj;
    const float v = (isw3 && col >= 10) ? 0.f : w[col * 256 + k];
    const short hi = f2bf(v);
    wfm[j] = (term == 0) ? hi : f2bf(v - bf2f(hi));
  }

  // ==== phase 0b: conv (R9 verbatim), samples 2*bid, 2*bid+1 ====
  {
    const int n0 = bid * 2;

    bf16x8 Wf[2][4][2];  // [tap][ntile][kstep]
#pragma unroll
    for (int tap = 0; tap < 2; ++tap) {
      const float* wsrc = tap ? cw1 : cw0;
#pragma unroll
      for (int ntl = 0; ntl < 4; ++ntl)
#pragma unroll
        for (int ks = 0; ks < 2; ++ks) {
          const int ch = wv * 64 + ntl * 16 + r;
          const float* p = wsrc + ch * 64 + ks * 32 + g * 8;
          const float4 a = *reinterpret_cast<const float4*>(p);
          const float4 b = *reinterpret_cast<const float4*>(p + 4);
          bf16x8 fr;
          fr[0] = f2bf(a.x); fr[1] = f2bf(a.y); fr[2] = f2bf(a.z); fr[3] = f2bf(a.w);
          fr[4] = f2bf(b.x); fr[5] = f2bf(b.y); fr[6] = f2bf(b.z); fr[7] = f2bf(b.w);
          Wf[tap][ntl][ks] = fr;
        }
    }
    float cbv[4];
#pragma unroll
    for (int ntl = 0; ntl < 4; ++ntl) cbv[ntl] = cb[wv * 64 + ntl * 16 + r];

    for (int s = 0; s < 2; ++s) {
      const float4* xg = reinterpret_cast<const float4*>(x + (size_t)(n0 + s) * (NOBJ * 64));
      for (int i = t; i < 400; i += 256) {
        float4 v = xg[i];
        s16x4 p;
        p.x = f2bf(v.x); p.y = f2bf(v.y); p.z = f2bf(v.z); p.w = f2bf(v.w);
        *reinterpret_cast<s16x4*>(&xs[s][i >> 4][(i & 15) * 4]) = p;
      }
    }
    __syncthreads();

    for (int s = 0; s < 2; ++s) {
      bf16x8 Xf[2][2];  // rows 25..31 garbage, outputs unread
#pragma unroll
      for (int mt = 0; mt < 2; ++mt)
#pragma unroll
        for (int ks = 0; ks < 2; ++ks)
          Xf[mt][ks] = *reinterpret_cast<const bf16x8*>(&xs[s][mt * 16 + r][ks * 32 + g * 8]);

      f32x4 acc[2][2][4];  // [tap][mtile][ntile]
#pragma unroll
      for (int tap = 0; tap < 2; ++tap)
#pragma unroll
        for (int mt = 0; mt < 2; ++mt)
#pragma unroll
          for (int ntl = 0; ntl < 4; ++ntl) {
            f32x4 z = {0.f, 0.f, 0.f, 0.f};
            acc[tap][mt][ntl] = z;
          }

#pragma unroll
      for (int tap = 0; tap < 2; ++tap)
#pragma unroll
        for (int mt = 0; mt < 2; ++mt)
#pragma unroll
          for (int ntl = 0; ntl < 4; ++ntl)
#pragma unroll
            for (int ks = 0; ks < 2; ++ks)
              acc[tap][mt][ntl] = __builtin_amdgcn_mfma_f32_16x16x32_bf16(
                  Xf[mt][ks], Wf[tap][ntl][ks], acc[tap][mt][ntl], 0, 0, 0);

#pragma unroll
      for (int tap = 0; tap < 2; ++tap)
#pragma unroll
        for (int mt = 0; mt < 2; ++mt)
#pragma unroll
          for (int ntl = 0; ntl < 4; ++ntl) {
            const int cl = ntl * 16 + r;
            const int row0 = mt * 16 + g * 4;
            const float badd = (tap == 0) ? cbv[ntl] : 0.f;
#pragma unroll
            for (int q = 0; q < 4; ++q)
              if (row0 + q < NOBJ) ab[wv][tap][row0 + q][cl] = acc[tap][mt][ntl][q] + badd;
          }
      // same-wave LDS RAW ordered by lgkmcnt; ab wave-private -> no barrier

      float A[NOBJ], Bv[NOBJ];
#pragma unroll
      for (int i = 0; i < NOBJ; ++i) { A[i] = ab[wv][0][i][lane]; Bv[i] = ab[wv][1][i][lane]; }
      float hacc = 0.f;
#pragma unroll
      for (int d = 1; d < NOBJ; ++d) {
        float sd = 0.f;
#pragma unroll
        for (int i = 0; i + d < NOBJ; ++i) sd += fmaxf(A[i] + Bv[i + d], 0.f);
        hacc = __builtin_fmaf(sd, 1.0f / (float)(NOBJ - d), hacc);
      }
      h0p[(size_t)(n0 + s) * 256 + t] = packhl(hacc * (1.0f / (float)(NOBJ - 1)));
    }
  }

  grid_barrier(bar + 0, 512);

  // ==== phase 1/2: MLP layers, M=8 N=64 per block ====
  const int m0 = (bid >> 2) * 8;
  const int nt = (bid & 3) * 4 + wv;

#pragma unroll 1
  for (int L = 0; L < 2; ++L) {
    const uint* inp = (L == 0) ? h0p : h1p;
    uint* outp = (L == 0) ? h1p : h2p;
    const short* wl = wfm + L * 131072;
    const float* bias = (L == 0) ? b1 : b2;

    // stage A rows m0..m0+7 hi/lo into LDS (8 x 256, pitch 264)
    const uint4* p4 = reinterpret_cast<const uint4*>(inp) + m0 * 64;
#pragma unroll
    for (int it = 0; it < 2; ++it) {
      const int idx = t + 256 * it;  // 0..511
      const uint4 u = p4[idx];
      const int row = idx >> 6, c = (idx & 63) * 4;
      s16x4 hi4, lo4;
      hi4.x = (short)(u.x >> 16); lo4.x = (short)(u.x & 0xffff);
      hi4.y = (short)(u.y >> 16); lo4.y = (short)(u.y & 0xffff);
      hi4.z = (short)(u.z >> 16); lo4.z = (short)(u.z & 0xffff);
      hi4.w = (short)(u.w >> 16); lo4.w = (short)(u.w & 0xffff);
      *reinterpret_cast<s16x4*>(&Hs[0][row][c]) = hi4;
      *reinterpret_cast<s16x4*>(&Hs[1][row][c]) = lo4;
    }
    __syncthreads();

    bf16x8 ahi[8], alo[8];
#pragma unroll
    for (int ks = 0; ks < 8; ++ks) {
      const int ko = ks * 32 + g * 8;
      ahi[ks] = *reinterpret_cast<const bf16x8*>(&Hs[0][r & 7][ko]);
      alo[ks] = *reinterpret_cast<const bf16x8*>(&Hs[1][r & 7][ko]);
    }
    bf16x8 bh[8], bl[8];
#pragma unroll
    for (int ks = 0; ks < 8; ++ks) {
      bh[ks] = *reinterpret_cast<const bf16x8*>(wl + ((nt * 8 + ks) << 9) + lane * 8);
      bl[ks] = *reinterpret_cast<const bf16x8*>(wl + 65536 + ((nt * 8 + ks) << 9) + lane * 8);
    }
    const float bv = bias[nt * 16 + r];
    f32x4 acc = {bv, bv, bv, bv};
#pragma unroll
    for (int ks = 0; ks < 8; ++ks) {
      acc = __builtin_amdgcn_mfma_f32_16x16x32_bf16(ahi[ks], bh[ks], acc, 0, 0, 0);
      acc = __builtin_amdgcn_mfma_f32_16x16x32_bf16(alo[ks], bh[ks], acc, 0, 0, 0);
      acc = __builtin_amdgcn_mfma_f32_16x16x32_bf16(ahi[ks], bl[ks], acc, 0, 0, 0);
    }
    if (g < 2) {  // D rows 0..7 are the real rows
      const int col = nt * 16 + r;
#pragma unroll
      for (int q = 0; q < 4; ++q)
        outp[(size_t)(m0 + 4 * g + q) * 256 + col] = packhl(fmaxf(acc[q], 0.f));
    }
    grid_barrier(bar + 32 * (1 + L), 512);  // entry __syncthreads also guards Hs
  }

  // ==== phase 3: layer 3 (N=10 zero-padded to 16), blocks 0..127, wave 0 ====
  if (bid < 128 && wv == 0) {
    const int mm0 = bid * 8;
    bf16x8 ahi[8], alo[8], bh[8], bl[8];
#pragma unroll
    for (int ks = 0; ks < 8; ++ks) {
      const uint* pe = h2p + (size_t)(mm0 + (r & 7)) * 256 + ks * 32 + g * 8;
      const uint4 u0 = *reinterpret_cast<const uint4*>(pe);
      const uint4 u1 = *reinterpret_cast<const uint4*>(pe + 4);
      bf16x8 h8, l8;
      h8[0] = (short)(u0.x >> 16); l8[0] = (short)(u0.x & 0xffff);
      h8[1] = (short)(u0.y >> 16); l8[1] = (short)(u0.y & 0xffff);
      h8[2] = (short)(u0.z >> 16); l8[2] = (short)(u0.z & 0xffff);
      h8[3] = (short)(u0.w >> 16); l8[3] = (short)(u0.w & 0xffff);
      h8[4] = (short)(u1.x >> 16); l8[4] = (short)(u1.x & 0xffff);
      h8[5] = (short)(u1.y >> 16); l8[5] = (short)(u1.y & 0xffff);
      h8[6] = (short)(u1.z >> 16); l8[6] = (short)(u1.z & 0xffff);
      h8[7] = (short)(u1.w >> 16); l8[7] = (short)(u1.w & 0xffff);
      ahi[ks] = h8; alo[ks] = l8;
      bh[ks] = *reinterpret_cast<const bf16x8*>(wfm + 262144 + (ks << 9) + lane * 8);
      bl[ks] = *reinterpret_cast<const bf16x8*>(wfm + 262144 + 4096 + (ks << 9) + lane * 8);
    }
    const float bv = (r < 10) ? b3[r] : 0.f;
    f32x4 acc = {bv, bv, bv, bv};
#pragma unroll
    for (int ks = 0; ks < 8; ++ks) {
      acc = __builtin_amdgcn_mfma_f32_16x16x32_bf16(ahi[ks], bh[ks], acc, 0, 0, 0);
      acc = __builtin_amdgcn_mfma_f32_16x16x32_bf16(alo[ks], bh[ks], acc, 0, 0, 0);
      acc = __builtin_amdgcn_mfma_f32_16x16x32_bf16(ahi[ks], bl[ks], acc, 0, 0, 0);
    }
    if (g < 2 && r < 10) {  // rows 0..7 real
#pragma unroll
      for (int q = 0; q < 4; ++q)
        out[(size_t)(mm0 + 4 * g + q) * 10 + r] = acc[q];
    }
  }
}

extern "C" void kernel_launch(void* const* d_in, const int* in_sizes, int n_in,
                              void* d_out, int out_size, void* d_ws, size_t ws_size,
                              hipStream_t stream) {
  const float* x   = (const float*)d_in[0];
  const float* cw0 = (const float*)d_in[1];
  const float* cw1 = (const float*)d_in[2];
  const float* cb  = (const float*)d_in[3];
  const float* w1  = (const float*)d_in[4];
  const float* b1  = (const float*)d_in[5];
  const float* w2  = (const float*)d_in[6];
  const float* b2  = (const float*)d_in[7];
  const float* w3  = (const float*)d_in[8];
  const float* b3  = (const float*)d_in[9];
  float* out = (float*)d_out;

  uint* h0p = (uint*)d_ws;                        // 1 MB packed
  uint* h1p = h0p + 262144;                       // 1 MB packed
  uint* h2p = h1p + 262144;                       // 1 MB packed
  short* wfm = (short*)(h2p + 262144);            // 540 KB frag-linear weights
  uint* bar = (uint*)((char*)d_ws + (4 << 20));   // 3 counters, 128B stride

  hipMemsetAsync(bar, 0, 512, stream);            // graph-capturable memset node
  mono_kernel<<<512, 256, 0, stream>>>(x, cw0, cw1, cb, w1, w2, w3,
                                       b1, b2, b3, wfm, h0p, h1p, h2p, bar, out);
}

// Round 12
// 35.695 us; speedup vs baseline: 4.2580x; 4.2580x over previous
//
#include <hip/hip_runtime.h>
#include <hip/hip_bf16.h>

#define NOBJ 25

typedef short bf16x8 __attribute__((ext_vector_type(8)));
typedef short s16x4 __attribute__((ext_vector_type(4)));
typedef float f32x4 __attribute__((ext_vector_type(4)));
typedef unsigned int uint;

__device__ __forceinline__ short f2bf(float f) {
  __hip_bfloat16 b = __float2bfloat16(f);  // RTN
  return *reinterpret_cast<short*>(&b);
}
__device__ __forceinline__ float bf2f(short s) {
  unsigned u = ((unsigned)(unsigned short)s) << 16;
  return __uint_as_float(u);
}
__device__ __forceinline__ uint packhl(float v) {
  const short hi = f2bf(v);
  const short lo = f2bf(v - bf2f(hi));
  return ((uint)(unsigned short)hi << 16) | (uint)(unsigned short)lo;
}

// ---------------------------------------------------------------------------
// prep: MLP weights -> hi/lo bf16, fragment-linear (R9 verbatim).
// ---------------------------------------------------------------------------
__global__ __launch_bounds__(256) void prep_kernel(
    const float* __restrict__ w1, const float* __restrict__ w2,
    const float* __restrict__ w3, short* __restrict__ wfm) {
  for (int j = blockIdx.x * 256 + threadIdx.x; j < 270336; j += 264 * 256) {
    const float* w; int term, f, nt;
    const bool isw3 = (j >= 262144);
    if (!isw3) {
      w = (j >> 17) ? w2 : w1;
      const int idx = j & 131071;
      term = idx >> 16; f = idx & 65535; nt = f >> 12;
    } else {
      w = w3;
      const int idx = j - 262144;  // 0..8191
      term = idx >> 12; f = idx & 4095; nt = 0;
    }
    const int ks = (f >> 9) & 7;
    const int l  = (f >> 3) & 63;
    const int jj = f & 7;
    const int col = nt * 16 + (l & 15);
    const int k   = ks * 32 + (l >> 4) * 8 + jj;
    const float v = (isw3 && col >= 10) ? 0.f : w[col * 256 + k];
    const short hi = f2bf(v);
    wfm[j] = (term == 0) ? hi : f2bf(v - bf2f(hi));
  }
}

// ---------------------------------------------------------------------------
// conv: R9 algorithm verbatim. ONE change: waves_per_eu pinned to (2,2).
// LDS (63.6KB) already caps occupancy at 2 blocks/CU = 2 waves/EU; without
// the pin the allocator targets 4 waves/EU (<=128 VGPR) and rematerializes
// the pairwise A/B arrays as ~600 extra ds_read_b32/wave/sample (the ~20us
// LDS-bound pathology; evidence: VGPR=80/88 in R6/R11). Pinning grants the
// 256-VGPR budget so Wf/acc/A/Bv stay resident.
// ---------------------------------------------------------------------------
__global__
__attribute__((amdgpu_flat_work_group_size(256, 256)))
__attribute__((amdgpu_waves_per_eu(2, 2)))
void conv_kernel(
    const float* __restrict__ x,    // (1024, 25*64)
    const float* __restrict__ cw0,  // (256, 64)
    const float* __restrict__ cw1,  // (256, 64)
    const float* __restrict__ cb,   // (256)
    uint* __restrict__ h0p)         // (1024, 256) packed hi|lo bf16
{
  __shared__ short xs[2][32][72];        // 9216 B
  __shared__ float ab[4][2][NOBJ][68];   // 54400 B (per-wave scratch)

  const int t = threadIdx.x;
  const int lane = t & 63;
  const int wv = t >> 6;
  const int r = lane & 15;
  const int g = lane >> 4;
  const int n0 = blockIdx.x * 2;

  bf16x8 Wf[2][4][2];  // [tap][ntile][kstep]
#pragma unroll
  for (int tap = 0; tap < 2; ++tap) {
    const float* wsrc = tap ? cw1 : cw0;
#pragma unroll
    for (int ntl = 0; ntl < 4; ++ntl)
#pragma unroll
      for (int ks = 0; ks < 2; ++ks) {
        const int ch = wv * 64 + ntl * 16 + r;
        const float* p = wsrc + ch * 64 + ks * 32 + g * 8;
        const float4 a = *reinterpret_cast<const float4*>(p);
        const float4 b = *reinterpret_cast<const float4*>(p + 4);
        bf16x8 fr;
        fr[0] = f2bf(a.x); fr[1] = f2bf(a.y); fr[2] = f2bf(a.z); fr[3] = f2bf(a.w);
        fr[4] = f2bf(b.x); fr[5] = f2bf(b.y); fr[6] = f2bf(b.z); fr[7] = f2bf(b.w);
        Wf[tap][ntl][ks] = fr;
      }
  }
  float cbv[4];
#pragma unroll
  for (int ntl = 0; ntl < 4; ++ntl) cbv[ntl] = cb[wv * 64 + ntl * 16 + r];

  for (int s = 0; s < 2; ++s) {
    const float4* xg = reinterpret_cast<const float4*>(x + (size_t)(n0 + s) * (NOBJ * 64));
    for (int i = t; i < 400; i += 256) {
      float4 v = xg[i];
      s16x4 p;
      p.x = f2bf(v.x); p.y = f2bf(v.y); p.z = f2bf(v.z); p.w = f2bf(v.w);
      *reinterpret_cast<s16x4*>(&xs[s][i >> 4][(i & 15) * 4]) = p;
    }
  }
  __syncthreads();

  for (int s = 0; s < 2; ++s) {
    bf16x8 Xf[2][2];  // rows 25..31 garbage, outputs unread
#pragma unroll
    for (int mt = 0; mt < 2; ++mt)
#pragma unroll
      for (int ks = 0; ks < 2; ++ks)
        Xf[mt][ks] = *reinterpret_cast<const bf16x8*>(&xs[s][mt * 16 + r][ks * 32 + g * 8]);

    f32x4 acc[2][2][4];  // [tap][mtile][ntile]
#pragma unroll
    for (int tap = 0; tap < 2; ++tap)
#pragma unroll
      for (int mt = 0; mt < 2; ++mt)
#pragma unroll
        for (int ntl = 0; ntl < 4; ++ntl) {
          f32x4 z = {0.f, 0.f, 0.f, 0.f};
          acc[tap][mt][ntl] = z;
        }

#pragma unroll
    for (int tap = 0; tap < 2; ++tap)
#pragma unroll
      for (int mt = 0; mt < 2; ++mt)
#pragma unroll
        for (int ntl = 0; ntl < 4; ++ntl)
#pragma unroll
          for (int ks = 0; ks < 2; ++ks)
            acc[tap][mt][ntl] = __builtin_amdgcn_mfma_f32_16x16x32_bf16(
                Xf[mt][ks], Wf[tap][ntl][ks], acc[tap][mt][ntl], 0, 0, 0);

#pragma unroll
    for (int tap = 0; tap < 2; ++tap)
#pragma unroll
      for (int mt = 0; mt < 2; ++mt)
#pragma unroll
        for (int ntl = 0; ntl < 4; ++ntl) {
          const int cl = ntl * 16 + r;
          const int row0 = mt * 16 + g * 4;
          const float badd = (tap == 0) ? cbv[ntl] : 0.f;
#pragma unroll
          for (int q = 0; q < 4; ++q)
            if (row0 + q < NOBJ) ab[wv][tap][row0 + q][cl] = acc[tap][mt][ntl][q] + badd;
        }
    // same-wave LDS RAW ordered by lgkmcnt; ab wave-private -> no barrier

    float A[NOBJ], Bv[NOBJ];
#pragma unroll
    for (int i = 0; i < NOBJ; ++i) { A[i] = ab[wv][0][i][lane]; Bv[i] = ab[wv][1][i][lane]; }
    float hacc = 0.f;
#pragma unroll
    for (int d = 1; d < NOBJ; ++d) {
      float sd = 0.f;
#pragma unroll
      for (int i = 0; i + d < NOBJ; ++i) sd += fmaxf(A[i] + Bv[i + d], 0.f);
      hacc = __builtin_fmaf(sd, 1.0f / (float)(NOBJ - d), hacc);
    }
    h0p[(size_t)(n0 + s) * 256 + t] = packhl(hacc * (1.0f / (float)(NOBJ - 1)));
  }
}

// ---------------------------------------------------------------------------
// mlp_mid: one layer, out = relu(in @ W^T + b), packed hi|lo (R9 verbatim).
// ---------------------------------------------------------------------------
__global__ __launch_bounds__(256, 1) void mlp_mid(
    const uint* __restrict__ inp,   // (1024,256) packed
    const short* __restrict__ wl,   // this layer's frag-linear weights (lo @ +65536)
    const float* __restrict__ bias,
    uint* __restrict__ outp)        // (1024,256) packed
{
  __shared__ short Hs[2][16][272];  // [term][row][k] 17408 B
  const int t = threadIdx.x, lane = t & 63, wv = t >> 6;
  const int r = lane & 15, g = lane >> 4;
  const int m0 = (blockIdx.x >> 2) * 16;
  const int nt = (blockIdx.x & 3) * 4 + wv;

  const uint4* p4 = reinterpret_cast<const uint4*>(inp) + m0 * 64;
#pragma unroll
  for (int it = 0; it < 4; ++it) {
    const int idx = t + 256 * it;
    const uint4 u = p4[idx];
    const int row = idx >> 6, c = (idx & 63) * 4;
    s16x4 hi4, lo4;
    hi4.x = (short)(u.x >> 16); lo4.x = (short)(u.x & 0xffff);
    hi4.y = (short)(u.y >> 16); lo4.y = (short)(u.y & 0xffff);
    hi4.z = (short)(u.z >> 16); lo4.z = (short)(u.z & 0xffff);
    hi4.w = (short)(u.w >> 16); lo4.w = (short)(u.w & 0xffff);
    *reinterpret_cast<s16x4*>(&Hs[0][row][c]) = hi4;
    *reinterpret_cast<s16x4*>(&Hs[1][row][c]) = lo4;
  }
  __syncthreads();

  bf16x8 ahi[8], alo[8];
#pragma unroll
  for (int ks = 0; ks < 8; ++ks) {
    ahi[ks] = *reinterpret_cast<const bf16x8*>(&Hs[0][r][ks * 32 + g * 8]);
    alo[ks] = *reinterpret_cast<const bf16x8*>(&Hs[1][r][ks * 32 + g * 8]);
  }
  bf16x8 bh[8], bl[8];
#pragma unroll
  for (int ks = 0; ks < 8; ++ks) {
    bh[ks] = *reinterpret_cast<const bf16x8*>(wl + ((nt * 8 + ks) << 9) + lane * 8);
    bl[ks] = *reinterpret_cast<const bf16x8*>(wl + 65536 + ((nt * 8 + ks) << 9) + lane * 8);
  }
  const float bv = bias[nt * 16 + r];
  f32x4 acc = {bv, bv, bv, bv};
#pragma unroll
  for (int ks = 0; ks < 8; ++ks) {
    acc = __builtin_amdgcn_mfma_f32_16x16x32_bf16(ahi[ks], bh[ks], acc, 0, 0, 0);
    acc = __builtin_amdgcn_mfma_f32_16x16x32_bf16(alo[ks], bh[ks], acc, 0, 0, 0);
    acc = __builtin_amdgcn_mfma_f32_16x16x32_bf16(ahi[ks], bl[ks], acc, 0, 0, 0);
  }
  const int col = nt * 16 + r;
#pragma unroll
  for (int q = 0; q < 4; ++q)
    outp[(size_t)(m0 + 4 * g + q) * 256 + col] = packhl(fmaxf(acc[q], 0.f));
}

// ---------------------------------------------------------------------------
// mlp_last: out = in @ w3^T + b3 (N=10 zero-padded to 16), R9 verbatim.
// ---------------------------------------------------------------------------
__global__ __launch_bounds__(64, 1) void mlp_last(
    const uint* __restrict__ inp,   // (1024,256) packed
    const short* __restrict__ wf,   // wfm base (layer3 at +262144)
    const float* __restrict__ b3,
    float* __restrict__ out)        // (1024, 10)
{
  const int lane = threadIdx.x & 63;
  const int r = lane & 15, g = lane >> 4;
  const int m0 = blockIdx.x * 16;

  bf16x8 ahi[8], alo[8], bh[8], bl[8];
#pragma unroll
  for (int ks = 0; ks < 8; ++ks) {
    const uint* pe = inp + (size_t)(m0 + r) * 256 + ks * 32 + g * 8;
    const uint4 u0 = *reinterpret_cast<const uint4*>(pe);
    const uint4 u1 = *reinterpret_cast<const uint4*>(pe + 4);
    bf16x8 h8, l8;
    h8[0] = (short)(u0.x >> 16); l8[0] = (short)(u0.x & 0xffff);
    h8[1] = (short)(u0.y >> 16); l8[1] = (short)(u0.y & 0xffff);
    h8[2] = (short)(u0.z >> 16); l8[2] = (short)(u0.z & 0xffff);
    h8[3] = (short)(u0.w >> 16); l8[3] = (short)(u0.w & 0xffff);
    h8[4] = (short)(u1.x >> 16); l8[4] = (short)(u1.x & 0xffff);
    h8[5] = (short)(u1.y >> 16); l8[5] = (short)(u1.y & 0xffff);
    h8[6] = (short)(u1.z >> 16); l8[6] = (short)(u1.z & 0xffff);
    h8[7] = (short)(u1.w >> 16); l8[7] = (short)(u1.w & 0xffff);
    ahi[ks] = h8; alo[ks] = l8;
    bh[ks] = *reinterpret_cast<const bf16x8*>(wf + 262144 + (ks << 9) + lane * 8);
    bl[ks] = *reinterpret_cast<const bf16x8*>(wf + 262144 + 4096 + (ks << 9) + lane * 8);
  }
  const float bv = (r < 10) ? b3[r] : 0.f;
  f32x4 acc = {bv, bv, bv, bv};
#pragma unroll
  for (int ks = 0; ks < 8; ++ks) {
    acc = __builtin_amdgcn_mfma_f32_16x16x32_bf16(ahi[ks], bh[ks], acc, 0, 0, 0);
    acc = __builtin_amdgcn_mfma_f32_16x16x32_bf16(alo[ks], bh[ks], acc, 0, 0, 0);
    acc = __builtin_amdgcn_mfma_f32_16x16x32_bf16(ahi[ks], bl[ks], acc, 0, 0, 0);
  }
  if (r < 10) {
#pragma unroll
    for (int q = 0; q < 4; ++q)
      out[(size_t)(m0 + 4 * g + q) * 10 + r] = acc[q];
  }
}

extern "C" void kernel_launch(void* const* d_in, const int* in_sizes, int n_in,
                              void* d_out, int out_size, void* d_ws, size_t ws_size,
                              hipStream_t stream) {
  const float* x   = (const float*)d_in[0];
  const float* cw0 = (const float*)d_in[1];
  const float* cw1 = (const float*)d_in[2];
  const float* cb  = (const float*)d_in[3];
  const float* w1  = (const float*)d_in[4];
  const float* b1  = (const float*)d_in[5];
  const float* w2  = (const float*)d_in[6];
  const float* b2  = (const float*)d_in[7];
  const float* w3  = (const float*)d_in[8];
  const float* b3  = (const float*)d_in[9];
  float* out = (float*)d_out;

  uint* h0p = (uint*)d_ws;            // 1 MB packed
  uint* h1p = h0p + 262144;           // 1 MB packed
  uint* h2p = h1p + 262144;           // 1 MB packed
  short* wfm = (short*)(h2p + 262144);// 540 KB frag-linear weights

  prep_kernel<<<264, 256, 0, stream>>>(w1, w2, w3, wfm);
  conv_kernel<<<512, 256, 0, stream>>>(x, cw0, cw1, cb, h0p);
  mlp_mid<<<256, 256, 0, stream>>>(h0p, wfm, b1, h1p);
  mlp_mid<<<256, 256, 0, stream>>>(h1p, wfm + 131072, b2, h2p);
  mlp_last<<<64, 64, 0, stream>>>(h2p, wfm, b3, out);
}

// Round 13
// 34.199 us; speedup vs baseline: 4.4443x; 1.0437x over previous
//
#include <hip/hip_runtime.h>
#include <hip/hip_bf16.h>

#define NOBJ 25

typedef short bf16x8 __attribute__((ext_vector_type(8)));
typedef short s16x4 __attribute__((ext_vector_type(4)));
typedef float f32x4 __attribute__((ext_vector_type(4)));
typedef unsigned int uint;

__device__ __forceinline__ short f2bf(float f) {
  __hip_bfloat16 b = __float2bfloat16(f);  // RTN
  return *reinterpret_cast<short*>(&b);
}
__device__ __forceinline__ float bf2f(short s) {
  unsigned u = ((unsigned)(unsigned short)s) << 16;
  return __uint_as_float(u);
}
__device__ __forceinline__ uint packhl(float v) {
  const short hi = f2bf(v);
  const short lo = f2bf(v - bf2f(hi));
  return ((uint)(unsigned short)hi << 16) | (uint)(unsigned short)lo;
}

// ---------------------------------------------------------------------------
// K1: blocks 0..127  : MLP weight prep (hi/lo bf16, fragment-linear);
//     blocks 128..639: conv taps via bf16 MFMA + wave-local pairwise pool
//                      (R9-verified body), h written packed hi|lo.
// x staging is issued BEFORE the Wf loads so the two cold-miss trains overlap.
// ---------------------------------------------------------------------------
__global__ __launch_bounds__(256, 2) void conv_prep_kernel(
    const float* __restrict__ x,    // (1024, 25*64)
    const float* __restrict__ cw0,  // (256, 64)
    const float* __restrict__ cw1,  // (256, 64)
    const float* __restrict__ cb,   // (256)
    const float* __restrict__ w1, const float* __restrict__ w2,
    const float* __restrict__ w3,
    uint* __restrict__ h0p,         // (1024, 256) packed hi|lo bf16
    short* __restrict__ wfm)        // 270336 shorts, fragment-linear hi/lo
{
  __shared__ short xs[2][32][72];        // 9216 B
  __shared__ float ab[4][2][NOBJ][68];   // 54400 B (per-wave scratch)

  if (blockIdx.x < 128) {
    // ---- MLP weight prep: layer L at L*131072: [term][nt][ks][lane][j];
    // layer 3 at 262144: [term][ks][lane][j], cols>=10 zero-padded.
    // value = w[(nt*16+(lane&15))*256 + ks*32 + (lane>>4)*8 + j]
    for (int j = blockIdx.x * 256 + threadIdx.x; j < 270336; j += 128 * 256) {
      const float* w; int term, f, nt;
      const bool isw3 = (j >= 262144);
      if (!isw3) {
        w = (j >> 17) ? w2 : w1;
        const int idx = j & 131071;
        term = idx >> 16; f = idx & 65535; nt = f >> 12;
      } else {
        w = w3;
        const int idx = j - 262144;  // 0..8191
        term = idx >> 12; f = idx & 4095; nt = 0;
      }
      const int ks = (f >> 9) & 7;
      const int l  = (f >> 3) & 63;
      const int jj = f & 7;
      const int col = nt * 16 + (l & 15);
      const int k   = ks * 32 + (l >> 4) * 8 + jj;
      const float v = (isw3 && col >= 10) ? 0.f : w[col * 256 + k];
      const short hi = f2bf(v);
      wfm[j] = (term == 0) ? hi : f2bf(v - bf2f(hi));
    }
    return;
  }

  // ---- conv branch ----
  const int t = threadIdx.x;
  const int lane = t & 63;
  const int wv = t >> 6;
  const int r = lane & 15;
  const int g = lane >> 4;
  const int n0 = (blockIdx.x - 128) * 2;

  // x staging first (cold HBM misses issued early)
  for (int s = 0; s < 2; ++s) {
    const float4* xg = reinterpret_cast<const float4*>(x + (size_t)(n0 + s) * (NOBJ * 64));
    for (int i = t; i < 400; i += 256) {
      float4 v = xg[i];
      s16x4 p;
      p.x = f2bf(v.x); p.y = f2bf(v.y); p.z = f2bf(v.z); p.w = f2bf(v.w);
      *reinterpret_cast<s16x4*>(&xs[s][i >> 4][(i & 15) * 4]) = p;
    }
  }

  // W fragments for both taps (overlaps with staging misses)
  bf16x8 Wf[2][4][2];  // [tap][ntile][kstep]
#pragma unroll
  for (int tap = 0; tap < 2; ++tap) {
    const float* wsrc = tap ? cw1 : cw0;
#pragma unroll
    for (int ntl = 0; ntl < 4; ++ntl)
#pragma unroll
      for (int ks = 0; ks < 2; ++ks) {
        const int ch = wv * 64 + ntl * 16 + r;
        const float* p = wsrc + ch * 64 + ks * 32 + g * 8;
        const float4 a = *reinterpret_cast<const float4*>(p);
        const float4 b = *reinterpret_cast<const float4*>(p + 4);
        bf16x8 fr;
        fr[0] = f2bf(a.x); fr[1] = f2bf(a.y); fr[2] = f2bf(a.z); fr[3] = f2bf(a.w);
        fr[4] = f2bf(b.x); fr[5] = f2bf(b.y); fr[6] = f2bf(b.z); fr[7] = f2bf(b.w);
        Wf[tap][ntl][ks] = fr;
      }
  }
  float cbv[4];
#pragma unroll
  for (int ntl = 0; ntl < 4; ++ntl) cbv[ntl] = cb[wv * 64 + ntl * 16 + r];

  __syncthreads();

  for (int s = 0; s < 2; ++s) {
    bf16x8 Xf[2][2];  // rows 25..31 garbage, outputs unread
#pragma unroll
    for (int mt = 0; mt < 2; ++mt)
#pragma unroll
      for (int ks = 0; ks < 2; ++ks)
        Xf[mt][ks] = *reinterpret_cast<const bf16x8*>(&xs[s][mt * 16 + r][ks * 32 + g * 8]);

    f32x4 acc[2][2][4];  // [tap][mtile][ntile]
#pragma unroll
    for (int tap = 0; tap < 2; ++tap)
#pragma unroll
      for (int mt = 0; mt < 2; ++mt)
#pragma unroll
        for (int ntl = 0; ntl < 4; ++ntl) {
          f32x4 z = {0.f, 0.f, 0.f, 0.f};
          acc[tap][mt][ntl] = z;
        }

#pragma unroll
    for (int tap = 0; tap < 2; ++tap)
#pragma unroll
      for (int mt = 0; mt < 2; ++mt)
#pragma unroll
        for (int ntl = 0; ntl < 4; ++ntl)
#pragma unroll
          for (int ks = 0; ks < 2; ++ks)
            acc[tap][mt][ntl] = __builtin_amdgcn_mfma_f32_16x16x32_bf16(
                Xf[mt][ks], Wf[tap][ntl][ks], acc[tap][mt][ntl], 0, 0, 0);

    // wave-local scatter (D: col=lane&15 -> channel, row=4g+q -> object)
#pragma unroll
    for (int tap = 0; tap < 2; ++tap)
#pragma unroll
      for (int mt = 0; mt < 2; ++mt)
#pragma unroll
        for (int ntl = 0; ntl < 4; ++ntl) {
          const int cl = ntl * 16 + r;
          const int row0 = mt * 16 + g * 4;
          const float badd = (tap == 0) ? cbv[ntl] : 0.f;
#pragma unroll
          for (int q = 0; q < 4; ++q)
            if (row0 + q < NOBJ) ab[wv][tap][row0 + q][cl] = acc[tap][mt][ntl][q] + badd;
        }
    // same-wave LDS RAW ordered by lgkmcnt; ab wave-private -> no barrier

    float A[NOBJ], Bv[NOBJ];
#pragma unroll
    for (int i = 0; i < NOBJ; ++i) { A[i] = ab[wv][0][i][lane]; Bv[i] = ab[wv][1][i][lane]; }
    float hacc = 0.f;
#pragma unroll
    for (int d = 1; d < NOBJ; ++d) {
      float sd = 0.f;
#pragma unroll
      for (int i = 0; i + d < NOBJ; ++i) sd += fmaxf(A[i] + Bv[i + d], 0.f);
      hacc = __builtin_fmaf(sd, 1.0f / (float)(NOBJ - d), hacc);
    }
    h0p[(size_t)(n0 + s) * 256 + t] = packhl(hacc * (1.0f / (float)(NOBJ - 1)));
  }
}

// ---------------------------------------------------------------------------
// K2: full 3-layer MLP, one kernel. 64 blocks x 512 threads, M=16 rows/block,
// weights full-streamed per block (64 x 528KB = 34MB L2 demand). Wave wv owns
// cols [32wv, 32wv+32) (nt = wv*2+ntl). Per layer: bulk-load 16 hi-B frags ->
// 32 MFMAs -> bulk-load 16 lo-B frags -> 16 MFMAs. H hi/lo ping-pong in LDS.
// Layer 3 (N=10 zero-padded) on wave 0.
// ---------------------------------------------------------------------------
__global__ __launch_bounds__(512, 1) void mlp_fused(
    const uint* __restrict__ inp,   // (1024,256) packed hi|lo
    const short* __restrict__ wf,   // fragment-linear hi/lo weights
    const float* __restrict__ b1, const float* __restrict__ b2,
    const float* __restrict__ b3,
    float* __restrict__ out)        // (1024, 10)
{
  __shared__ short Hs[2][2][16][272];  // [pp][term][row][k] 34816 B
  const int t = threadIdx.x, lane = t & 63, wv = t >> 6;
  const int r = lane & 15, g = lane >> 4;
  const int m0 = blockIdx.x * 16;

  // stage 16 rows packed -> hi/lo LDS
  const uint4* p4 = reinterpret_cast<const uint4*>(inp) + m0 * 64;
#pragma unroll
  for (int it = 0; it < 2; ++it) {
    const int idx = t + 512 * it;  // 0..1023
    const uint4 u = p4[idx];
    const int row = idx >> 6, c = (idx & 63) * 4;
    s16x4 hi4, lo4;
    hi4.x = (short)(u.x >> 16); lo4.x = (short)(u.x & 0xffff);
    hi4.y = (short)(u.y >> 16); lo4.y = (short)(u.y & 0xffff);
    hi4.z = (short)(u.z >> 16); lo4.z = (short)(u.z & 0xffff);
    hi4.w = (short)(u.w >> 16); lo4.w = (short)(u.w & 0xffff);
    *reinterpret_cast<s16x4*>(&Hs[0][0][row][c]) = hi4;
    *reinterpret_cast<s16x4*>(&Hs[0][1][row][c]) = lo4;
  }
  __syncthreads();

  int pp = 0;
  const float* bias[2] = {b1, b2};
#pragma unroll
  for (int L = 0; L < 2; ++L) {
    const short* wl = wf + L * 131072;

    bf16x8 ahi[8], alo[8];
#pragma unroll
    for (int ks = 0; ks < 8; ++ks) {
      const int ko = ks * 32 + g * 8;
      ahi[ks] = *reinterpret_cast<const bf16x8*>(&Hs[pp][0][r][ko]);
      alo[ks] = *reinterpret_cast<const bf16x8*>(&Hs[pp][1][r][ko]);
    }

    f32x4 acc[2];
#pragma unroll
    for (int ntl = 0; ntl < 2; ++ntl) {
      const float bv = bias[L][(wv * 2 + ntl) * 16 + r];
      f32x4 a = {bv, bv, bv, bv};
      acc[ntl] = a;
    }

    {  // hi-B bulk load, then 32 MFMAs (ahi*bhi + alo*bhi)
      bf16x8 bh[2][8];
#pragma unroll
      for (int ntl = 0; ntl < 2; ++ntl)
#pragma unroll
        for (int ks = 0; ks < 8; ++ks)
          bh[ntl][ks] = *reinterpret_cast<const bf16x8*>(
              wl + (((wv * 2 + ntl) * 8 + ks) << 9) + lane * 8);
#pragma unroll
      for (int ks = 0; ks < 8; ++ks)
#pragma unroll
        for (int ntl = 0; ntl < 2; ++ntl) {
          acc[ntl] = __builtin_amdgcn_mfma_f32_16x16x32_bf16(ahi[ks], bh[ntl][ks], acc[ntl], 0, 0, 0);
          acc[ntl] = __builtin_amdgcn_mfma_f32_16x16x32_bf16(alo[ks], bh[ntl][ks], acc[ntl], 0, 0, 0);
        }
    }
    {  // lo-B bulk load, then 16 MFMAs (ahi*blo)
      bf16x8 bl[2][8];
#pragma unroll
      for (int ntl = 0; ntl < 2; ++ntl)
#pragma unroll
        for (int ks = 0; ks < 8; ++ks)
          bl[ntl][ks] = *reinterpret_cast<const bf16x8*>(
              wl + 65536 + (((wv * 2 + ntl) * 8 + ks) << 9) + lane * 8);
#pragma unroll
      for (int ks = 0; ks < 8; ++ks)
#pragma unroll
        for (int ntl = 0; ntl < 2; ++ntl)
          acc[ntl] = __builtin_amdgcn_mfma_f32_16x16x32_bf16(ahi[ks], bl[ntl][ks], acc[ntl], 0, 0, 0);
    }

    // writeback relu(acc) hi/lo into the other buffer (all 16 rows real)
#pragma unroll
    for (int ntl = 0; ntl < 2; ++ntl) {
      const int col = (wv * 2 + ntl) * 16 + r;
#pragma unroll
      for (int q = 0; q < 4; ++q) {
        const float v = fmaxf(acc[ntl][q], 0.f);
        const int row = 4 * g + q;
        const short hi = f2bf(v);
        Hs[pp ^ 1][0][row][col] = hi;
        Hs[pp ^ 1][1][row][col] = f2bf(v - bf2f(hi));
      }
    }
    __syncthreads();
    pp ^= 1;
  }

  // layer 3: one 16x16 tile (cols 10..15 zero-padded), wave 0 only
  if (wv == 0) {
    const float bv = (r < 10) ? b3[r] : 0.f;
    f32x4 acc = {bv, bv, bv, bv};
    bf16x8 ahi[8], alo[8], bh[8], bl[8];
#pragma unroll
    for (int ks = 0; ks < 8; ++ks) {
      const int ko = ks * 32 + g * 8;
      ahi[ks] = *reinterpret_cast<const bf16x8*>(&Hs[pp][0][r][ko]);
      alo[ks] = *reinterpret_cast<const bf16x8*>(&Hs[pp][1][r][ko]);
      bh[ks] = *reinterpret_cast<const bf16x8*>(wf + 262144 + (ks << 9) + lane * 8);
      bl[ks] = *reinterpret_cast<const bf16x8*>(wf + 262144 + 4096 + (ks << 9) + lane * 8);
    }
#pragma unroll
    for (int ks = 0; ks < 8; ++ks) {
      acc = __builtin_amdgcn_mfma_f32_16x16x32_bf16(ahi[ks], bh[ks], acc, 0, 0, 0);
      acc = __builtin_amdgcn_mfma_f32_16x16x32_bf16(alo[ks], bh[ks], acc, 0, 0, 0);
      acc = __builtin_amdgcn_mfma_f32_16x16x32_bf16(ahi[ks], bl[ks], acc, 0, 0, 0);
    }
    if (r < 10) {
#pragma unroll
      for (int q = 0; q < 4; ++q)
        out[(size_t)(m0 + 4 * g + q) * 10 + r] = acc[q];
    }
  }
}

extern "C" void kernel_launch(void* const* d_in, const int* in_sizes, int n_in,
                              void* d_out, int out_size, void* d_ws, size_t ws_size,
                              hipStream_t stream) {
  const float* x   = (const float*)d_in[0];
  const float* cw0 = (const float*)d_in[1];
  const float* cw1 = (const float*)d_in[2];
  const float* cb  = (const float*)d_in[3];
  const float* w1  = (const float*)d_in[4];
  const float* b1  = (const float*)d_in[5];
  const float* w2  = (const float*)d_in[6];
  const float* b2  = (const float*)d_in[7];
  const float* w3  = (const float*)d_in[8];
  const float* b3  = (const float*)d_in[9];
  float* out = (float*)d_out;

  uint* h0p = (uint*)d_ws;             // 1 MB packed hi|lo
  short* wfm = (short*)(h0p + 262144); // 540 KB frag-linear weights

  conv_prep_kernel<<<640, 256, 0, stream>>>(x, cw0, cw1, cb, w1, w2, w3, h0p, wfm);
  mlp_fused<<<64, 512, 0, stream>>>(h0p, wfm, b1, b2, b3, out);
}